// Round 1
// baseline (4935.518 us; speedup 1.0000x reference)
//
#include <hip/hip_runtime.h>
#include <hip/hip_bf16.h>
#include <cstdint>
#include <cstddef>

// Dims (fixed by the reference)
#define BB 32     // batch
#define SC 64     // context length
#define TT 64     // decode steps
#define HH 256    // hidden
#define G3 768    // 3*H
#define VV 32000  // vocab

__device__ __forceinline__ float sigmf(float x) { return 1.f / (1.f + __expf(-x)); }

// ---------------------------------------------------------------------------
// Kernel A: precompute GI_enc[s][b][g] = enc_emb[ctx[b][s]] . enc_Wih[g] + bih[g]
// Grid: 64 * 24 blocks (24 chunks of 32 gate-rows), 256 threads.
// Each block: one context position s, all 32 b, 32 g rows.
// ---------------------------------------------------------------------------
__global__ __launch_bounds__(256) void gi_pre_kernel(
    const int* __restrict__ ctx, const float* __restrict__ emb,
    const float* __restrict__ Wih, const float* __restrict__ bih,
    float* __restrict__ GI)
{
    __shared__ float4 xl[BB][HH / 4];   // 32 KB: embedded tokens for this s
    __shared__ int tokl[BB];
    const int bid = blockIdx.x;
    const int s  = bid / 24;
    const int g0 = (bid % 24) * 32;
    const int t  = threadIdx.x;

    if (t < BB) tokl[t] = ctx[t * SC + s];     // context[b][s]
    __syncthreads();
    #pragma unroll
    for (int i = 0; i < 8; ++i) {
        int f = t + 256 * i;                   // 0..2047 over [32 b][64 float4]
        int b = f >> 6, c = f & 63;
        xl[b][c] = ((const float4*)(emb + (size_t)tokl[b] * HH))[c];
    }
    __syncthreads();

    const int gl = t & 31, bq = t >> 5;        // gate row + batch quad
    const float4* wr = (const float4*)(Wih + (size_t)(g0 + gl) * HH);
    float a0 = 0.f, a1 = 0.f, a2 = 0.f, a3 = 0.f;
    #pragma unroll 4
    for (int k = 0; k < HH / 4; ++k) {
        float4 w  = wr[k];
        float4 x0 = xl[bq * 4 + 0][k];
        float4 x1 = xl[bq * 4 + 1][k];
        float4 x2 = xl[bq * 4 + 2][k];
        float4 x3 = xl[bq * 4 + 3][k];
        a0 += w.x * x0.x + w.y * x0.y + w.z * x0.z + w.w * x0.w;
        a1 += w.x * x1.x + w.y * x1.y + w.z * x1.z + w.w * x1.w;
        a2 += w.x * x2.x + w.y * x2.y + w.z * x2.z + w.w * x2.w;
        a3 += w.x * x3.x + w.y * x3.y + w.z * x3.z + w.w * x3.w;
    }
    const float bv = bih[g0 + gl];
    GI[(size_t)(s * BB + bq * 4 + 0) * G3 + g0 + gl] = a0 + bv;
    GI[(size_t)(s * BB + bq * 4 + 1) * G3 + g0 + gl] = a1 + bv;
    GI[(size_t)(s * BB + bq * 4 + 2) * G3 + g0 + gl] = a2 + bv;
    GI[(size_t)(s * BB + bq * 4 + 3) * G3 + g0 + gl] = a3 + bv;
}

// ---------------------------------------------------------------------------
// Kernel B: full recurrence, one block per batch element (32 blocks x 768 thr).
// enc_outs kept in LDS; output probs gathered per gold token only.
// ---------------------------------------------------------------------------
__global__ __launch_bounds__(768, 1) void seq_kernel(
    const int*   __restrict__ inp,
    const float* __restrict__ GI,
    const float* __restrict__ eWhh, const float* __restrict__ ebhh,
    const float* __restrict__ demb,
    const float* __restrict__ Wc,   const float* __restrict__ bc,
    const float* __restrict__ dWih, const float* __restrict__ dWhh,
    const float* __restrict__ dbih, const float* __restrict__ dbhh,
    const float* __restrict__ Wo,   const float* __restrict__ bo,
    float* __restrict__ out)
{
    __shared__ float eo[SC][HH];   // 64 KB encoder outputs
    __shared__ float h[HH];
    __shared__ float gg[G3];       // gh
    __shared__ float gi2[G3];      // decoder gi
    __shared__ float sc[SC];       // scores -> attn
    __shared__ float ctxv[HH];
    __shared__ float xv[HH];
    __shared__ float xb[HH];       // relu-input base (emb_sos part)

    const int b = blockIdx.x;
    const int t = threadIdx.x;

    // init h = 0, and xbase[j] = b_comb[j] + emb_sos . W_comb[j, 0:256]
    if (t < HH) {
        h[t] = 0.f;
        float a = bc[t];
        const float* wr = Wc + (size_t)t * (2 * HH);
        const float* es = demb + HH;           // SOS_INDEX = 1
        #pragma unroll 4
        for (int k = 0; k < HH; ++k) a += es[k] * wr[k];
        xb[t] = a;
    }
    __syncthreads();

    // ---------------- encoder: 64 GRU steps ----------------
    const float4* whr = (const float4*)(eWhh + (size_t)t * HH);
    const float  ebh  = ebhh[t];
    for (int s = 0; s < SC; ++s) {
        float acc = 0.f;
        const float4* hv4 = (const float4*)h;
        #pragma unroll 4
        for (int k = 0; k < HH / 4; ++k) {
            float4 w = whr[k]; float4 hv = hv4[k];
            acc += w.x * hv.x + w.y * hv.y + w.z * hv.z + w.w * hv.w;
        }
        gg[t] = acc + ebh;
        __syncthreads();
        if (t < HH) {
            const float* gis = GI + (size_t)(s * BB + b) * G3;
            float r = sigmf(gis[t] + gg[t]);
            float z = sigmf(gis[HH + t] + gg[HH + t]);
            float n = tanhf(gis[2 * HH + t] + r * gg[2 * HH + t]);
            float hn = (1.f - z) * n + z * h[t];
            h[t] = hn;
            eo[s][t] = hn;
        }
        __syncthreads();
    }

    // ---------------- decoder: 64 attention-GRU steps ----------------
    const float4* wi4 = (const float4*)(dWih + (size_t)t * HH);
    const float4* wh4 = (const float4*)(dWhh + (size_t)t * HH);
    const float  dbi = dbih[t];
    const float  dbh = dbhh[t];
    for (int di = 0; di < TT; ++di) {
        // D1: attention scores[s] = eo[s] . h   (4 lanes per s, staggered k)
        if (t < 256) {
            const int s = t >> 2, c = t & 3;
            float acc = 0.f;
            #pragma unroll 4
            for (int k = 0; k < 64; ++k) {
                int kk = ((k + s + c * 16) & 63) + c * 64;  // bank-staggered
                acc += eo[s][kk] * h[kk];
            }
            acc += __shfl_xor(acc, 1);
            acc += __shfl_xor(acc, 2);
            if (c == 0) sc[s] = acc;
        }
        __syncthreads();
        // D2: softmax over 64 scores (wave 0)
        if (t < 64) {
            float v = sc[t];
            float m = v;
            #pragma unroll
            for (int off = 32; off; off >>= 1) m = fmaxf(m, __shfl_xor(m, off));
            float e = __expf(v - m);
            float su = e;
            #pragma unroll
            for (int off = 32; off; off >>= 1) su += __shfl_xor(su, off);
            sc[t] = e / su;
        }
        __syncthreads();
        // D3: ctx[j] = sum_s attn[s] * eo[s][j]
        if (t < HH) {
            float a = 0.f;
            #pragma unroll 4
            for (int s = 0; s < SC; ++s) a += sc[s] * eo[s][t];
            ctxv[t] = a;
        }
        __syncthreads();
        // D4: x[j] = relu(xbase[j] + ctx . W_comb[j, 256:512])
        if (t < HH) {
            float a = xb[t];
            const float4* wr = (const float4*)(Wc + (size_t)t * (2 * HH) + HH);
            const float4* cv = (const float4*)ctxv;
            #pragma unroll 4
            for (int k = 0; k < HH / 4; ++k) {
                float4 w = wr[k]; float4 c4 = cv[k];
                a += w.x * c4.x + w.y * c4.y + w.z * c4.z + w.w * c4.w;
            }
            xv[t] = fmaxf(a, 0.f);
        }
        __syncthreads();
        // D5: gi[g] = x . dWih[g] + bih ; gh[g] = h . dWhh[g] + bhh
        {
            const float4* x4 = (const float4*)xv;
            const float4* h4 = (const float4*)h;
            float ai = 0.f, ah = 0.f;
            #pragma unroll 2
            for (int k = 0; k < HH / 4; ++k) {
                float4 wa = wi4[k], wb = wh4[k];
                float4 xx = x4[k], hh2 = h4[k];
                ai += wa.x * xx.x + wa.y * xx.y + wa.z * xx.z + wa.w * xx.w;
                ah += wb.x * hh2.x + wb.y * hh2.y + wb.z * hh2.z + wb.w * hh2.w;
            }
            gi2[t] = ai + dbi;
            gg[t]  = ah + dbh;
        }
        __syncthreads();
        // D6: GRU elementwise update
        if (t < HH) {
            float r = sigmf(gi2[t] + gg[t]);
            float z = sigmf(gi2[HH + t] + gg[HH + t]);
            float n = tanhf(gi2[2 * HH + t] + r * gg[2 * HH + t]);
            h[t] = (1.f - z) * n + z * h[t];
        }
        __syncthreads();
        // D7: p_tok = sigmoid(h . W_out[tok] + b_out[tok])  (wave 0)
        if (t < 64) {
            const int tok = inp[b * TT + di];
            const float4* wo = (const float4*)(Wo + (size_t)tok * HH);
            float4 w  = wo[t];
            float4 hv = ((const float4*)h)[t];
            float a = w.x * hv.x + w.y * hv.y + w.z * hv.z + w.w * hv.w;
            #pragma unroll
            for (int off = 32; off; off >>= 1) a += __shfl_xor(a, off);
            if (t == 0) out[1 + b * TT + di] = sigmf(a + bo[tok]);
        }
        // no extra sync needed: next D1 only reads h/eo; sc rewritten after sync
    }
}

// ---------------------------------------------------------------------------
// Kernel C: BCE loss over the 2048 gathered probabilities -> out[0]
// ---------------------------------------------------------------------------
__global__ __launch_bounds__(256) void loss_kernel(const int* __restrict__ ts,
                                                   float* __restrict__ out)
{
    __shared__ float red[4];
    const int t = threadIdx.x;
    const float tv = (float)ts[0];
    float sum = 0.f;
    for (int i = t; i < BB * TT; i += 256) {
        float p = out[1 + i];
        float lp  = fmaxf(__logf(p), -100.f);
        float l1p = fmaxf(__logf(1.f - p), -100.f);
        sum += tv * lp + (1.f - tv) * l1p;
    }
    #pragma unroll
    for (int off = 32; off; off >>= 1) sum += __shfl_xor(sum, off);
    if ((t & 63) == 0) red[t >> 6] = sum;
    __syncthreads();
    if (t == 0) out[0] = -(red[0] + red[1] + red[2] + red[3]) / (float)(BB * TT);
}

// ---------------------------------------------------------------------------
extern "C" void kernel_launch(void* const* d_in, const int* in_sizes, int n_in,
                              void* d_out, int out_size, void* d_ws, size_t ws_size,
                              hipStream_t stream)
{
    const int*   ctx     = (const int*)d_in[0];
    const int*   inp     = (const int*)d_in[1];
    const int*   ts      = (const int*)d_in[2];
    const float* enc_emb = (const float*)d_in[3];
    const float* eWih    = (const float*)d_in[4];
    const float* eWhh    = (const float*)d_in[5];
    const float* ebih    = (const float*)d_in[6];
    const float* ebhh    = (const float*)d_in[7];
    const float* demb    = (const float*)d_in[8];
    const float* Wc      = (const float*)d_in[9];
    const float* bc      = (const float*)d_in[10];
    const float* dWih    = (const float*)d_in[11];
    const float* dWhh    = (const float*)d_in[12];
    const float* dbih    = (const float*)d_in[13];
    const float* dbhh    = (const float*)d_in[14];
    const float* Wo      = (const float*)d_in[15];
    const float* bo      = (const float*)d_in[16];
    float* out = (float*)d_out;
    float* GI  = (float*)d_ws;   // 64*32*768 f32 = 6.29 MB

    hipLaunchKernelGGL(gi_pre_kernel, dim3(SC * 24), dim3(256), 0, stream,
                       ctx, enc_emb, eWih, ebih, GI);
    hipLaunchKernelGGL(seq_kernel, dim3(BB), dim3(G3), 0, stream,
                       inp, GI, eWhh, ebhh, demb, Wc, bc,
                       dWih, dWhh, dbih, dbhh, Wo, bo, out);
    hipLaunchKernelGGL(loss_kernel, dim3(1), dim3(256), 0, stream, ts, out);
}

// Round 2
// 894.702 us; speedup vs baseline: 5.5164x; 5.5164x over previous
//
#include <hip/hip_runtime.h>
#include <hip/hip_bf16.h>
#include <cstdint>
#include <cstddef>

// Dims (fixed by the reference)
#define BB 32     // batch
#define SC 64     // context length
#define TT 64     // decode steps
#define HH 256    // hidden
#define G3 768    // 3*H
#define VV 32000  // vocab

__device__ __forceinline__ float sigmf(float x) { return 1.f / (1.f + __expf(-x)); }

// ---------------------------------------------------------------------------
// Kernel A: precompute GI_enc[s][b][g] = enc_emb[ctx[b][s]] . enc_Wih[g] + bih[g]
// ---------------------------------------------------------------------------
__global__ __launch_bounds__(256) void gi_pre_kernel(
    const int* __restrict__ ctx, const float* __restrict__ emb,
    const float* __restrict__ Wih, const float* __restrict__ bih,
    float* __restrict__ GI)
{
    __shared__ float4 xl[BB][HH / 4];   // 32 KB: embedded tokens for this s
    __shared__ int tokl[BB];
    const int bid = blockIdx.x;
    const int s  = bid / 24;
    const int g0 = (bid % 24) * 32;
    const int t  = threadIdx.x;

    if (t < BB) tokl[t] = ctx[t * SC + s];     // context[b][s]
    __syncthreads();
    #pragma unroll
    for (int i = 0; i < 8; ++i) {
        int f = t + 256 * i;                   // 0..2047 over [32 b][64 float4]
        int b = f >> 6, c = f & 63;
        xl[b][c] = ((const float4*)(emb + (size_t)tokl[b] * HH))[c];
    }
    __syncthreads();

    const int gl = t & 31, bq = t >> 5;        // gate row + batch quad
    const float4* wr = (const float4*)(Wih + (size_t)(g0 + gl) * HH);
    float a0 = 0.f, a1 = 0.f, a2 = 0.f, a3 = 0.f;
    #pragma unroll 4
    for (int k = 0; k < HH / 4; ++k) {
        float4 w  = wr[k];
        float4 x0 = xl[bq * 4 + 0][k];
        float4 x1 = xl[bq * 4 + 1][k];
        float4 x2 = xl[bq * 4 + 2][k];
        float4 x3 = xl[bq * 4 + 3][k];
        a0 += w.x * x0.x + w.y * x0.y + w.z * x0.z + w.w * x0.w;
        a1 += w.x * x1.x + w.y * x1.y + w.z * x1.z + w.w * x1.w;
        a2 += w.x * x2.x + w.y * x2.y + w.z * x2.z + w.w * x2.w;
        a3 += w.x * x3.x + w.y * x3.y + w.z * x3.z + w.w * x3.w;
    }
    const float bv = bih[g0 + gl];
    GI[(size_t)(s * BB + bq * 4 + 0) * G3 + g0 + gl] = a0 + bv;
    GI[(size_t)(s * BB + bq * 4 + 1) * G3 + g0 + gl] = a1 + bv;
    GI[(size_t)(s * BB + bq * 4 + 2) * G3 + g0 + gl] = a2 + bv;
    GI[(size_t)(s * BB + bq * 4 + 3) * G3 + g0 + gl] = a3 + bv;
}

// ---------------------------------------------------------------------------
// Kernel B: full recurrence, one block per batch element (32 blocks x 768 thr).
// All recurrent weights live in REGISTERS (one gate-row per thread).
// ---------------------------------------------------------------------------
__global__ __launch_bounds__(768, 1) void seq_kernel(
    const int*   __restrict__ inp,
    const float* __restrict__ GI,
    const float* __restrict__ eWhh, const float* __restrict__ ebhh,
    const float* __restrict__ demb,
    const float* __restrict__ Wc,   const float* __restrict__ bc,
    const float* __restrict__ dWih, const float* __restrict__ dWhh,
    const float* __restrict__ dbih, const float* __restrict__ dbhh,
    const float* __restrict__ Wo,   const float* __restrict__ bo,
    float* __restrict__ out)
{
    __shared__ float eo[SC][HH];   // 64 KB encoder outputs
    __shared__ float h[HH];
    __shared__ float gg[G3];       // gh
    __shared__ float gi2[G3];      // decoder gi
    __shared__ float sc[SC];       // scores -> attn
    __shared__ float ctxv[HH];
    __shared__ float xv[HH];
    __shared__ float xb[HH];       // relu-input base (emb_sos part)
    __shared__ int   tokl[TT];

    const int b = blockIdx.x;
    const int t = threadIdx.x;

    if (t < TT) tokl[t] = inp[b * TT + t];

    // init h = 0, and xbase[j] = b_comb[j] + emb_sos . W_comb[j, 0:256]
    if (t < HH) {
        h[t] = 0.f;
        float a = bc[t];
        const float4* wr = (const float4*)(Wc + (size_t)t * (2 * HH));
        const float4* es = (const float4*)(demb + HH);      // SOS_INDEX = 1
        #pragma unroll
        for (int k = 0; k < HH / 4; ++k) {
            float4 w = wr[k], e = es[k];
            a += w.x * e.x + w.y * e.y + w.z * e.z + w.w * e.w;
        }
        xb[t] = a;
    }

    // ================= encoder =================
    {
        // preload this thread's eWhh row into registers (64 VGPRs)
        float4 wER[16];
        {
            const float4* pe = (const float4*)(eWhh + (size_t)t * HH);
            #pragma unroll
            for (int k = 0; k < 16; ++k) wER[k] = pe[k];
        }
        const float ebh = ebhh[t];

        // GI register double-buffer: preload s = 0
        float g0 = 0.f, g1 = 0.f, g2 = 0.f;
        if (t < HH) {
            const float* gp = GI + (size_t)b * G3;
            g0 = gp[t]; g1 = gp[HH + t]; g2 = gp[2 * HH + t];
        }
        __syncthreads();

        for (int s = 0; s < SC; ++s) {
            // prefetch next step's GI (covers matvec + barrier + elementwise)
            float gn0 = 0.f, gn1 = 0.f, gn2 = 0.f;
            if (t < HH && s + 1 < SC) {
                const float* gp = GI + (size_t)((s + 1) * BB + b) * G3;
                gn0 = gp[t]; gn1 = gp[HH + t]; gn2 = gp[2 * HH + t];
            }
            // gh[t] = h . eWhh[t] + bhh[t]
            float acc = 0.f;
            const float4* hv4 = (const float4*)h;
            #pragma unroll
            for (int k = 0; k < 16; ++k) {
                float4 w = wER[k]; float4 hv = hv4[k];
                acc += w.x * hv.x + w.y * hv.y + w.z * hv.z + w.w * hv.w;
            }
            gg[t] = acc + ebh;
            __syncthreads();
            if (t < HH) {
                float r = sigmf(g0 + gg[t]);
                float z = sigmf(g1 + gg[HH + t]);
                float n = tanhf(g2 + r * gg[2 * HH + t]);
                float hn = (1.f - z) * n + z * h[t];
                h[t] = hn;
                eo[s][t] = hn;
            }
            g0 = gn0; g1 = gn1; g2 = gn2;
            __syncthreads();
        }
    }

    // ================= decoder =================
    // preload this thread's dWih/dWhh rows + (t<256) W_comb right-half row
    float4 wIR[16], wHR[16], wCR[16];
    {
        const float4* pi = (const float4*)(dWih + (size_t)t * HH);
        const float4* ph = (const float4*)(dWhh + (size_t)t * HH);
        #pragma unroll
        for (int k = 0; k < 16; ++k) { wIR[k] = pi[k]; wHR[k] = ph[k]; }
        if (t < HH) {
            const float4* pc = (const float4*)(Wc + (size_t)t * (2 * HH) + HH);
            #pragma unroll
            for (int k = 0; k < 16; ++k) wCR[k] = pc[k];
        }
    }
    const float dbi = dbih[t];
    const float dbh = dbhh[t];

    for (int di = 0; di < TT; ++di) {
        // prefetch W_out[tok] row + b_out[tok] (consumed in D7, ~4000 cy later)
        float4 wo = {0.f, 0.f, 0.f, 0.f};
        float bov = 0.f;
        if (t < 64) {
            const int tok = tokl[di];
            wo  = ((const float4*)(Wo + (size_t)tok * HH))[t];
            bov = bo[tok];
        }
        // D1: attention scores[s] = eo[s] . h   (4 lanes per s, staggered k)
        if (t < 256) {
            const int s = t >> 2, c = t & 3;
            float acc = 0.f;
            #pragma unroll 4
            for (int k = 0; k < 64; ++k) {
                int kk = ((k + s + c * 16) & 63) + c * 64;  // bank-staggered
                acc += eo[s][kk] * h[kk];
            }
            acc += __shfl_xor(acc, 1);
            acc += __shfl_xor(acc, 2);
            if (c == 0) sc[s] = acc;
        }
        __syncthreads();
        // D2: softmax over 64 scores (wave 0)
        if (t < 64) {
            float v = sc[t];
            float m = v;
            #pragma unroll
            for (int off = 32; off; off >>= 1) m = fmaxf(m, __shfl_xor(m, off));
            float e = __expf(v - m);
            float su = e;
            #pragma unroll
            for (int off = 32; off; off >>= 1) su += __shfl_xor(su, off);
            sc[t] = e / su;
        }
        __syncthreads();
        // D3: ctx[j] = sum_s attn[s] * eo[s][j]
        if (t < HH) {
            float a = 0.f;
            #pragma unroll 4
            for (int s = 0; s < SC; ++s) a += sc[s] * eo[s][t];
            ctxv[t] = a;
        }
        __syncthreads();
        // D4: x[j] = relu(xbase[j] + ctx . W_comb[j, 256:512])
        if (t < HH) {
            float a = xb[t];
            const float4* cv = (const float4*)ctxv;
            #pragma unroll
            for (int k = 0; k < 16; ++k) {
                float4 w = wCR[k]; float4 c4 = cv[k];
                a += w.x * c4.x + w.y * c4.y + w.z * c4.z + w.w * c4.w;
            }
            xv[t] = fmaxf(a, 0.f);
        }
        __syncthreads();
        // D5: gi[g] = x . dWih[g] + bih ; gh[g] = h . dWhh[g] + bhh
        {
            const float4* x4 = (const float4*)xv;
            const float4* h4 = (const float4*)h;
            float ai = 0.f, ah = 0.f;
            #pragma unroll
            for (int k = 0; k < 16; ++k) {
                float4 wa = wIR[k], wb = wHR[k];
                float4 xx = x4[k], hh2 = h4[k];
                ai += wa.x * xx.x + wa.y * xx.y + wa.z * xx.z + wa.w * xx.w;
                ah += wb.x * hh2.x + wb.y * hh2.y + wb.z * hh2.z + wb.w * hh2.w;
            }
            gi2[t] = ai + dbi;
            gg[t]  = ah + dbh;
        }
        __syncthreads();
        // D6: GRU elementwise update
        if (t < HH) {
            float r = sigmf(gi2[t] + gg[t]);
            float z = sigmf(gi2[HH + t] + gg[HH + t]);
            float n = tanhf(gi2[2 * HH + t] + r * gg[2 * HH + t]);
            h[t] = (1.f - z) * n + z * h[t];
        }
        __syncthreads();
        // D7: p_tok = sigmoid(h . W_out[tok] + b_out[tok])  (wave 0)
        if (t < 64) {
            float4 hv = ((const float4*)h)[t];
            float a = wo.x * hv.x + wo.y * hv.y + wo.z * hv.z + wo.w * hv.w;
            #pragma unroll
            for (int off = 32; off; off >>= 1) a += __shfl_xor(a, off);
            if (t == 0) out[1 + b * TT + di] = sigmf(a + bov);
        }
        // no barrier needed: next D1 only reads h/eo; sc rewritten after sync
    }
}

// ---------------------------------------------------------------------------
// Kernel C: BCE loss over the 2048 gathered probabilities -> out[0]
// ---------------------------------------------------------------------------
__global__ __launch_bounds__(256) void loss_kernel(const int* __restrict__ ts,
                                                   float* __restrict__ out)
{
    __shared__ float red[4];
    const int t = threadIdx.x;
    const float tv = (float)ts[0];
    float sum = 0.f;
    for (int i = t; i < BB * TT; i += 256) {
        float p = out[1 + i];
        float lp  = fmaxf(__logf(p), -100.f);
        float l1p = fmaxf(__logf(1.f - p), -100.f);
        sum += tv * lp + (1.f - tv) * l1p;
    }
    #pragma unroll
    for (int off = 32; off; off >>= 1) sum += __shfl_xor(sum, off);
    if ((t & 63) == 0) red[t >> 6] = sum;
    __syncthreads();
    if (t == 0) out[0] = -(red[0] + red[1] + red[2] + red[3]) / (float)(BB * TT);
}

// ---------------------------------------------------------------------------
extern "C" void kernel_launch(void* const* d_in, const int* in_sizes, int n_in,
                              void* d_out, int out_size, void* d_ws, size_t ws_size,
                              hipStream_t stream)
{
    const int*   ctx     = (const int*)d_in[0];
    const int*   inp     = (const int*)d_in[1];
    const int*   ts      = (const int*)d_in[2];
    const float* enc_emb = (const float*)d_in[3];
    const float* eWih    = (const float*)d_in[4];
    const float* eWhh    = (const float*)d_in[5];
    const float* ebih    = (const float*)d_in[6];
    const float* ebhh    = (const float*)d_in[7];
    const float* demb    = (const float*)d_in[8];
    const float* Wc      = (const float*)d_in[9];
    const float* bc      = (const float*)d_in[10];
    const float* dWih    = (const float*)d_in[11];
    const float* dWhh    = (const float*)d_in[12];
    const float* dbih    = (const float*)d_in[13];
    const float* dbhh    = (const float*)d_in[14];
    const float* Wo      = (const float*)d_in[15];
    const float* bo      = (const float*)d_in[16];
    float* out = (float*)d_out;
    float* GI  = (float*)d_ws;   // 64*32*768 f32 = 6.29 MB

    hipLaunchKernelGGL(gi_pre_kernel, dim3(SC * 24), dim3(256), 0, stream,
                       ctx, enc_emb, eWih, ebih, GI);
    hipLaunchKernelGGL(seq_kernel, dim3(BB), dim3(G3), 0, stream,
                       inp, GI, eWhh, ebhh, demb, Wc, bc,
                       dWih, dWhh, dbih, dbhh, Wo, bo, out);
    hipLaunchKernelGGL(loss_kernel, dim3(1), dim3(256), 0, stream, ts, out);
}